// Round 1
// baseline (43.203 us; speedup 1.0000x reference)
//
#include <hip/hip_runtime.h>

// YOLO layer: input [B=16, A*C=255, G=76, G=76] f32, anchors [3,2] f32.
// Output [B, A*G*G=17328, C=85] f32.
// out[b][a*GG+pos][c] = f_c(in[((b*A+a)*85+c)*GG + pos])
//   c=0: (sigmoid+gx)*8, c=1: (sigmoid+gy)*8, c=2: exp*aw, c=3: exp*ah,
//   c>=4: sigmoid
// LDS-staged transpose: coalesced loads (spatial-contiguous) -> LDS [s][c]
// -> coalesced stores (channel-contiguous).

#define GDIM 76
#define GG 5776            // 76*76
#define NA 3
#define NCH 85
#define TILE 64            // spatial positions per block
#define THREADS 320        // 5 waves
#define ITERS 17           // 85*64/320

__global__ __launch_bounds__(THREADS) void yolo_kernel(
    const float* __restrict__ in, const float* __restrict__ anchors,
    float* __restrict__ out)
{
    __shared__ float lds[TILE * NCH];   // 21760 B

    const int tile = blockIdx.x;        // 0..90
    const int a    = blockIdx.y;        // 0..2
    const int b    = blockIdx.z;        // 0..15
    const int s0   = tile * TILE;
    const int ba   = b * NA + a;
    const int t    = threadIdx.x;

    // fold anchor/stride scaling: (exp(w)*(aw/8))*8 == exp(w)*aw (pow2 exact)
    const float aw = anchors[a * 2 + 0];
    const float ah = anchors[a * 2 + 1];

    const long in_base = (long)ba * NCH * GG;

    #pragma unroll
    for (int i = 0; i < ITERS; ++i) {
        int idx = t + i * THREADS;
        int c   = idx >> 6;       // channel 0..84 (wave-uniform)
        int s   = idx & 63;       // spatial within tile = lane
        int pos = s0 + s;
        if (pos < GG) {
            float v = in[in_base + (long)c * GG + pos];
            if (c == 0) {
                float gx = (float)(pos % GDIM);
                v = (1.0f / (1.0f + expf(-v)) + gx) * 8.0f;
            } else if (c == 1) {
                float gy = (float)(pos / GDIM);
                v = (1.0f / (1.0f + expf(-v)) + gy) * 8.0f;
            } else if (c == 2) {
                v = expf(v) * aw;
            } else if (c == 3) {
                v = expf(v) * ah;
            } else {
                v = 1.0f / (1.0f + expf(-v));
            }
            lds[s * NCH + c] = v;   // stride-85 write: 2-way bank alias = free
        }
    }

    __syncthreads();

    const int valid = (GG - s0 < TILE) ? (GG - s0) : TILE;
    const int nflat = valid * NCH;
    const long out_base = ((long)ba * GG + s0) * NCH;

    #pragma unroll
    for (int i = 0; i < ITERS; ++i) {
        int flat = t + i * THREADS;
        if (flat < nflat) {
            out[out_base + flat] = lds[flat];  // stride-1: coalesced, no conflicts
        }
    }
}

extern "C" void kernel_launch(void* const* d_in, const int* in_sizes, int n_in,
                              void* d_out, int out_size, void* d_ws, size_t ws_size,
                              hipStream_t stream) {
    const float* pred    = (const float*)d_in[0];
    const float* anchors = (const float*)d_in[1];
    float* out           = (float*)d_out;

    dim3 grid((GG + TILE - 1) / TILE, NA, 16);  // 91 x 3 x 16
    yolo_kernel<<<grid, THREADS, 0, stream>>>(pred, anchors, out);
}

// Round 2
// 38.121 us; speedup vs baseline: 1.1333x; 1.1333x over previous
//
#include <hip/hip_runtime.h>

// YOLO layer: input [B=16, A*C=255, G=76, G=76] f32, anchors [3,2] f32.
// Output [B, A*G*G=17328, C=85] f32.
// out[b][a*GG+pos][c] = f_c(in[((b*A+a)*85+c)*GG + pos])
//   c=0: (sigmoid+gx)*8, c=1: (sigmoid+gy)*8, c=2: exp*aw, c=3: exp*ah,
//   c>=4: sigmoid   (anchor/stride scaling folded: (e^w * aw/8)*8 == e^w*aw)
//
// LDS-staged transpose, fully vectorized:
//   load:  global_load_dwordx4 (4 spatial pos of one channel, coalesced)
//          -> 4x ds_write_b32 stride-85 (2 lanes/bank = conflict-free)
//   store: ds_read_b128 contiguous (conflict-free) -> global_store_dwordx4

#define GDIM 76
#define GG 5776            // 76*76 (divisible by 4 -> quads never straddle)
#define NA 3
#define NCH 85
#define TILE 64            // spatial positions per block
#define QUADS 16           // TILE/4
#define THREADS 256        // 4 waves
#define LOAD_UNITS (NCH * QUADS)        // 1360 float4 loads per tile
#define PHASE_ITERS 6                   // ceil(1360/256)

__global__ __launch_bounds__(THREADS) void yolo_kernel(
    const float* __restrict__ in, const float* __restrict__ anchors,
    float* __restrict__ out)
{
    __shared__ float lds[TILE * NCH];   // 21760 B -> 7 blocks/CU, 28 waves

    const int tile = blockIdx.x;        // 0..90
    const int a    = blockIdx.y;        // 0..2
    const int b    = blockIdx.z;        // 0..15
    const int s0   = tile * TILE;
    const int ba   = b * NA + a;
    const int t    = threadIdx.x;

    const float aw = anchors[a * 2 + 0];
    const float ah = anchors[a * 2 + 1];

    const float* inb = in + (long)ba * NCH * GG;

    #pragma unroll
    for (int i = 0; i < PHASE_ITERS; ++i) {
        int idx = t + i * THREADS;
        if (idx < LOAD_UNITS) {
            int c   = idx >> 4;         // channel 0..84 (4 channels per wave)
            int q   = idx & 15;         // quad within tile
            int pos = s0 + q * 4;
            if (pos < GG) {
                float4 v = *reinterpret_cast<const float4*>(&inb[(long)c * GG + pos]);
                float r[4] = {v.x, v.y, v.z, v.w};
                if (c == 0) {
                    #pragma unroll
                    for (int k = 0; k < 4; ++k) {
                        int p = pos + k;
                        float gx = (float)(p - (p / GDIM) * GDIM);
                        r[k] = (1.0f / (1.0f + expf(-r[k])) + gx) * 8.0f;
                    }
                } else if (c == 1) {
                    #pragma unroll
                    for (int k = 0; k < 4; ++k) {
                        int p = pos + k;
                        float gy = (float)(p / GDIM);
                        r[k] = (1.0f / (1.0f + expf(-r[k])) + gy) * 8.0f;
                    }
                } else if (c == 2) {
                    #pragma unroll
                    for (int k = 0; k < 4; ++k) r[k] = expf(r[k]) * aw;
                } else if (c == 3) {
                    #pragma unroll
                    for (int k = 0; k < 4; ++k) r[k] = expf(r[k]) * ah;
                } else {
                    #pragma unroll
                    for (int k = 0; k < 4; ++k) r[k] = 1.0f / (1.0f + expf(-r[k]));
                }
                #pragma unroll
                for (int k = 0; k < 4; ++k)
                    lds[(q * 4 + k) * NCH + c] = r[k];
            }
        }
    }

    __syncthreads();

    const int valid  = (GG - s0 < TILE) ? (GG - s0) : TILE;  // 64 or 16
    const int nflat4 = valid * NCH / 4;                       // divisible: 85*{64,16}
    float4* __restrict__ outv =
        reinterpret_cast<float4*>(out + ((long)ba * GG + s0) * NCH);
    const float4* ldsv = reinterpret_cast<const float4*>(lds);

    #pragma unroll
    for (int i = 0; i < PHASE_ITERS; ++i) {
        int f4 = t + i * THREADS;
        if (f4 < nflat4) {
            outv[f4] = ldsv[f4];   // ds_read_b128 + global_store_dwordx4
        }
    }
}

extern "C" void kernel_launch(void* const* d_in, const int* in_sizes, int n_in,
                              void* d_out, int out_size, void* d_ws, size_t ws_size,
                              hipStream_t stream) {
    const float* pred    = (const float*)d_in[0];
    const float* anchors = (const float*)d_in[1];
    float* out           = (float*)d_out;

    dim3 grid((GG + TILE - 1) / TILE, NA, 16);  // 91 x 3 x 16
    yolo_kernel<<<grid, THREADS, 0, stream>>>(pred, anchors, out);
}

// Round 3
// 37.236 us; speedup vs baseline: 1.1602x; 1.0238x over previous
//
#include <hip/hip_runtime.h>

// YOLO layer: input [B=16, A*C=255, G=76, G=76] f32, anchors [3,2] f32.
// Output [B, A*G*G=17328, C=85] f32.
//   c=0: (sigmoid+gx)*8, c=1: (sigmoid+gy)*8, c=2: exp*aw, c=3: exp*ah,
//   c>=4: sigmoid   (anchor/stride scaling folded: (e^w * aw/8)*8 == e^w*aw)
//
// Persistent grid-stride blocks + register pipeline:
//   while storing tile g (LDS -> global), the global loads for tile g+GRID
//   are already in flight into registers (T14 issue-early / write-late).
//   load:  global_load_dwordx4 (4 spatial pos of one channel, coalesced)
//   LDS:   ds_write_b32 stride-85 (2 lanes/bank = free), ds_read_b128 contig
//   store: global_store_dwordx4 (1024 B/wave-instr, contiguous)

#define GDIM 76
#define GG 5776            // 76*76 (divisible by 4)
#define NA 3
#define NCH 85
#define TILE 64            // spatial positions per block-tile
#define QUADS 16           // TILE/4
#define THREADS 256        // 4 waves
#define LOAD_UNITS (NCH * QUADS)   // 1360 float4 units per tile
#define LITERS 6                   // ceil(1360/256)
#define TPB 91                     // tiles per (b,a): ceil(5776/64)
#define NT (TPB * NA * 16)         // 4368 total tiles
#define GRID 1792                  // 7 blocks/CU * 256 CUs (LDS residency cap)

__global__ __launch_bounds__(THREADS) void yolo_kernel(
    const float* __restrict__ in, const float* __restrict__ anchors,
    float* __restrict__ out)
{
    __shared__ float lds[TILE * NCH];   // 21760 B -> 7 blocks/CU

    const int t = threadIdx.x;

    float4 v[LITERS];

    auto load_tile = [&](int g) {
        int ba   = g / TPB;
        int tile = g - ba * TPB;
        int s0   = tile * TILE;
        const float* inb = in + (long)ba * (NCH * GG);
        #pragma unroll
        for (int i = 0; i < LITERS; ++i) {
            int idx = t + i * THREADS;
            int c   = idx >> 4;
            int q   = idx & 15;
            int pos = s0 + q * 4;
            if (idx < LOAD_UNITS && pos < GG)
                v[i] = *reinterpret_cast<const float4*>(&inb[(long)c * GG + pos]);
        }
    };

    auto transform_write = [&](int g) {
        int ba   = g / TPB;
        int tile = g - ba * TPB;
        int a    = ba % NA;
        int s0   = tile * TILE;
        float aw = anchors[2 * a];
        float ah = anchors[2 * a + 1];
        #pragma unroll
        for (int i = 0; i < LITERS; ++i) {
            int idx = t + i * THREADS;
            int c   = idx >> 4;
            int q   = idx & 15;
            int pos = s0 + q * 4;
            if (idx < LOAD_UNITS && pos < GG) {
                float r[4] = {v[i].x, v[i].y, v[i].z, v[i].w};
                if (c == 0) {
                    #pragma unroll
                    for (int k = 0; k < 4; ++k) {
                        int p = pos + k;
                        float gx = (float)(p - (p / GDIM) * GDIM);
                        r[k] = (1.0f / (1.0f + expf(-r[k])) + gx) * 8.0f;
                    }
                } else if (c == 1) {
                    #pragma unroll
                    for (int k = 0; k < 4; ++k) {
                        int p = pos + k;
                        float gy = (float)(p / GDIM);
                        r[k] = (1.0f / (1.0f + expf(-r[k])) + gy) * 8.0f;
                    }
                } else if (c == 2) {
                    #pragma unroll
                    for (int k = 0; k < 4; ++k) r[k] = expf(r[k]) * aw;
                } else if (c == 3) {
                    #pragma unroll
                    for (int k = 0; k < 4; ++k) r[k] = expf(r[k]) * ah;
                } else {
                    #pragma unroll
                    for (int k = 0; k < 4; ++k) r[k] = 1.0f / (1.0f + expf(-r[k]));
                }
                #pragma unroll
                for (int k = 0; k < 4; ++k)
                    lds[(q * 4 + k) * NCH + c] = r[k];
            }
        }
    };

    auto store_tile = [&](int g) {
        int ba    = g / TPB;
        int tile  = g - ba * TPB;
        int s0    = tile * TILE;
        int valid = (GG - s0 < TILE) ? (GG - s0) : TILE;  // 64 or 16
        int n4    = valid * NCH / 4;                       // 1360 or 340
        float4* __restrict__ outv =
            reinterpret_cast<float4*>(out + ((long)ba * GG + s0) * NCH);
        const float4* ldsv = reinterpret_cast<const float4*>(lds);
        #pragma unroll
        for (int i = 0; i < LITERS; ++i) {
            int f4 = t + i * THREADS;
            if (f4 < n4)
                outv[f4] = ldsv[f4];
        }
    };

    int g = blockIdx.x;
    load_tile(g);                       // prologue (every block has >=2 tiles)
    for (; g < NT; g += GRID) {
        transform_write(g);             // consumes v (vmcnt wait), fills LDS
        __syncthreads();
        int gn = g + GRID;
        if (gn < NT) load_tile(gn);     // issue next-tile loads: overlap stores
        store_tile(g);                  // LDS -> global
        __syncthreads();                // LDS drained before next overwrite
    }
}

extern "C" void kernel_launch(void* const* d_in, const int* in_sizes, int n_in,
                              void* d_out, int out_size, void* d_ws, size_t ws_size,
                              hipStream_t stream) {
    const float* pred    = (const float*)d_in[0];
    const float* anchors = (const float*)d_in[1];
    float* out           = (float*)d_out;

    yolo_kernel<<<dim3(GRID), dim3(THREADS), 0, stream>>>(pred, anchors, out);
}